// Round 2
// 499.790 us; speedup vs baseline: 1.1469x; 1.1469x over previous
//
#include <hip/hip_runtime.h>
#include <math.h>
#include <cstddef>

// Geometry (fixed by the mock config)
#define BB    8
#define SS    4096
#define HH    2048
#define ROWS  (BB*SS)      // 32768 flattened (b,s) rows
#define NC    36           // 24 qkv-conv channels + 8 z + 2 b + 2 a
#define NCP   40           // padded weight row stride (16B-friendly)
#define KC    32           // K-chunk per LDS stage (per wave)
#define XST   33           // KC+1: LDS row stride (odd -> conflict-free reads)
#define KSL   256          // per-wave K slice (2048 / 8 waves)

// native 16B vector for nontemporal builtins (HIP float4 class is rejected)
typedef float vfloat4 __attribute__((ext_vector_type(4)));

// ws layout (floats). Required ws >= (131072 + 32768*36)*4 B ~= 5.3 MB.
#define MIX_OFF 131072     // mixed36[ROWS][36] after Wt[2048][40]

// ---------------------------------------------------------------------------
// Kernel 0: pack the four projection matrices into transposed Wt[k][c] so the
// GEMM inner loop reads one contiguous 36-float row per k via scalar loads.
__global__ __launch_bounds__(256) void pack_wt(
    const float* __restrict__ w_qkv, const float* __restrict__ w_z,
    const float* __restrict__ w_b,   const float* __restrict__ w_a,
    float* __restrict__ wt) {
  int idx = blockIdx.x * 256 + threadIdx.x;
  if (idx >= HH * NCP) return;
  int k = idx / NCP, c = idx - (idx / NCP) * NCP;
  float v = 0.f;
  if      (c < 24) v = w_qkv[c * HH + k];
  else if (c < 32) v = w_z[(c - 24) * HH + k];
  else if (c < 34) v = w_b[(c - 32) * HH + k];
  else if (c < 36) v = w_a[(c - 34) * HH + k];
  wt[idx] = v;
}

// ---------------------------------------------------------------------------
// Kernel 1: mixed36[r][c] = sum_k x[r][k] * Wt[k][c]   (r = b*S+s, c = 0..35)
// v3: 8 waves per block (512 thr), each wave owns a K/8 slice (256 k) of the
// same 64 rows; lane = row. 512 blocks x 8 waves = 4096 waves = 4 waves/SIMD
// (2x the previous grid-limited occupancy) to hide the SMEM weight-load
// latency. Per-wave-private LDS staging regions -> no barriers in main loop.
__global__ __launch_bounds__(512, 4) void proj36(
    const float* __restrict__ x, const float* __restrict__ wt,
    float* __restrict__ mix) {
  __shared__ float sm[8 * 64 * XST];         // 67.6 KB; reused for reduction
  const int tid  = threadIdx.x;
  const int lane = tid & 63;
  const int wv   = __builtin_amdgcn_readfirstlane(tid >> 6);
  const int r0   = blockIdx.x * 64;

  float* xs = sm + wv * 64 * XST;            // this wave's private region
  float acc[NC];
#pragma unroll
  for (int c = 0; c < NC; ++c) acc[c] = 0.f;

  const int kbase0 = wv * KSL;
  const int srow = lane >> 3;                // 8 rows per staging pass
  const int scol = (lane & 7) * 4;           // 8 lanes x float4 = 32 fl/row
  const float* xg = x + (size_t)r0 * HH + kbase0 + scol;

  float4 buf[8];
#pragma unroll
  for (int p = 0; p < 8; ++p)
    buf[p] = *(const float4*)(xg + (size_t)(p * 8 + srow) * HH);

  for (int ch = 0; ch < 8; ++ch) {
    // LDS write of current chunk (b32, odd stride -> conflict-free reads)
#pragma unroll
    for (int p = 0; p < 8; ++p) {
      float* dst = xs + (p * 8 + srow) * XST + scol;
      dst[0] = buf[p].x; dst[1] = buf[p].y; dst[2] = buf[p].z; dst[3] = buf[p].w;
    }
    // prefetch next chunk into registers (overlaps the compute below)
    if (ch < 7) {
      const float* xg2 = xg + (ch + 1) * KC;
#pragma unroll
      for (int p = 0; p < 8; ++p)
        buf[p] = *(const float4*)(xg2 + (size_t)(p * 8 + srow) * HH);
    }
    const float* wrow = wt + (size_t)(kbase0 + ch * KC) * NCP; // uniform -> s_load
    const float* xr = xs + lane * XST;
#pragma unroll 2
    for (int k = 0; k < KC; ++k) {
      float xv = xr[k];
#pragma unroll
      for (int c = 0; c < NC; ++c)
        acc[c] = fmaf(wrow[k * NCP + c], xv, acc[c]);
    }
    // no barrier: xs region is wave-private, in-wave DS ordering suffices
  }

  __syncthreads();                 // all waves done with staging regions
  // 8-way K reduction in two 32-row passes; layout red[8 waves][32 rows][37]
  const int myhalf = lane >> 5;
  const int rr = lane & 31;
  for (int half = 0; half < 2; ++half) {
    if (half) __syncthreads();     // previous pass done reading
    if (myhalf == half) {
#pragma unroll
      for (int c = 0; c < NC; ++c)
        sm[(wv * 32 + rr) * 37 + c] = acc[c];
    }
    __syncthreads();
    for (int idx = tid; idx < 32 * NC; idx += 512) {
      int row = idx / NC;
      float s = 0.f;
#pragma unroll
      for (int w = 0; w < 8; ++w) s += sm[(w * 32 + row) * 37 + (idx - row * NC)];
      mix[(size_t)(r0 + half * 32) * NC + idx] = s;   // coalesced 32x36 tile
    }
  }
}

// ---------------------------------------------------------------------------
// Kernel 2: causal depthwise conv + silu + gated-delta elementwise + RMSNorm
// + out-projection. v2: 32 rows per block (1024 blocks = 4/CU) for more
// store-stream parallelism; non-temporal stores for the 256 MB output.
__global__ __launch_bounds__(256) void fuse_out(
    const float* __restrict__ mix,  const float* __restrict__ conv_w,
    const float* __restrict__ dt_bias, const float* __restrict__ A_log,
    const float* __restrict__ norm_w,  const float* __restrict__ w_out,
    float* __restrict__ out) {
  __shared__ float m36[35 * 37];   // rows r0-3 .. r0+31, stride 37
  __shared__ float hb[32 * 8];
  const int tid = threadIdx.x;
  const int r0  = blockIdx.x * 32;

  // stage mixed36 tile (+3 halo rows for the conv)
  const long base = (long)(r0 - 3) * NC;
  for (int idx = tid; idx < 35 * NC; idx += 256) {
    int row = idx / NC, c = idx - row * NC;
    long g = base + idx;
    m36[row * 37 + c] = (g >= 0) ? mix[g] : 0.f;
  }
  __syncthreads();

  if (tid < 64) {                        // 2 threads per row (one per v-head)
    const int row  = tid >> 1, n = tid & 1;
    const int spos = (r0 + row) & (SS - 1);   // position within the batch
    float cv[12];
#pragma unroll
    for (int j = 0; j < 12; ++j) {
      int c = (j >> 2) * 8 + n * 4 + (j & 3); // q:0..7  k:8..15  v:16..23
      float s = 0.f;
#pragma unroll
      for (int k = 0; k < 4; ++k)
        if (spos + k - 3 >= 0) s += m36[(row + k) * 37 + c] * conv_w[c * 4 + k];
      cv[j] = s / (1.f + __expf(-s));         // silu
    }
    float bbv  = m36[(row + 3) * 37 + 32 + n];
    float aav  = m36[(row + 3) * 37 + 34 + n];
    float beta = 1.f / (1.f + __expf(-bbv));
    float spin = aav + dt_bias[n];
    float sp   = (spin > 20.f) ? spin : __logf(1.f + __expf(spin));
    float g    = -__expf(A_log[n]) * sp;
    float core[4], var = 0.f;
#pragma unroll
    for (int d = 0; d < 4; ++d) {
      core[d] = cv[8 + d] + beta * (cv[d] + cv[4 + d]) + g;
      var += core[d] * core[d];
    }
    float rs = rsqrtf(var * 0.25f + 1e-6f);
#pragma unroll
    for (int d = 0; d < 4; ++d) {
      float z = m36[(row + 3) * 37 + 24 + n * 4 + d];
      hb[row * 8 + n * 4 + d] =
          core[d] * rs * norm_w[d] * (z / (1.f + __expf(-z)));
    }
  }
  __syncthreads();

  // out-projection: thread owns cols [4t,4t+3] and [1024+4t, 1024+4t+3]
  const int c0a = tid * 4, c0b = 1024 + tid * 4;
  float4 wr[16];
#pragma unroll
  for (int i = 0; i < 4; ++i) {
    wr[i * 2]     = *(const float4*)(w_out + (size_t)(c0a + i) * 8);
    wr[i * 2 + 1] = *(const float4*)(w_out + (size_t)(c0a + i) * 8 + 4);
    wr[8 + i * 2]     = *(const float4*)(w_out + (size_t)(c0b + i) * 8);
    wr[8 + i * 2 + 1] = *(const float4*)(w_out + (size_t)(c0b + i) * 8 + 4);
  }
  for (int row = 0; row < 32; ++row) {
    float h[8];
#pragma unroll
    for (int v = 0; v < 8; ++v) h[v] = hb[row * 8 + v];   // LDS broadcast
    vfloat4 oa, ob;
#pragma unroll
    for (int i = 0; i < 4; ++i) {
      const float4 wa0 = wr[i * 2], wa1 = wr[i * 2 + 1];
      const float4 wb0 = wr[8 + i * 2], wb1 = wr[8 + i * 2 + 1];
      oa[i] = h[0]*wa0.x + h[1]*wa0.y + h[2]*wa0.z + h[3]*wa0.w
            + h[4]*wa1.x + h[5]*wa1.y + h[6]*wa1.z + h[7]*wa1.w;
      ob[i] = h[0]*wb0.x + h[1]*wb0.y + h[2]*wb0.z + h[3]*wb0.w
            + h[4]*wb1.x + h[5]*wb1.y + h[6]*wb1.z + h[7]*wb1.w;
    }
    float* op = out + (size_t)(r0 + row) * HH;
    __builtin_nontemporal_store(oa, (vfloat4*)(op + c0a));
    __builtin_nontemporal_store(ob, (vfloat4*)(op + c0b));
  }
}

// ---------------------------------------------------------------------------
extern "C" void kernel_launch(void* const* d_in, const int* in_sizes, int n_in,
                              void* d_out, int out_size, void* d_ws, size_t ws_size,
                              hipStream_t stream) {
  (void)in_sizes; (void)n_in; (void)out_size; (void)ws_size;
  const float* x      = (const float*)d_in[0];
  const float* w_qkv  = (const float*)d_in[1];
  const float* w_z    = (const float*)d_in[2];
  const float* w_b    = (const float*)d_in[3];
  const float* w_a    = (const float*)d_in[4];
  const float* w_out  = (const float*)d_in[5];
  const float* conv_w = (const float*)d_in[6];
  const float* dt_b   = (const float*)d_in[7];
  const float* A_log  = (const float*)d_in[8];
  const float* norm_w = (const float*)d_in[9];
  float* out = (float*)d_out;
  float* ws  = (float*)d_ws;
  float* wt  = ws;              // [2048][40]
  float* mix = ws + MIX_OFF;    // [32768][36]

  pack_wt<<<dim3((HH * NCP + 255) / 256), dim3(256), 0, stream>>>(
      w_qkv, w_z, w_b, w_a, wt);
  proj36<<<dim3(ROWS / 64), dim3(512), 0, stream>>>(x, wt, mix);
  fuse_out<<<dim3(ROWS / 32), dim3(256), 0, stream>>>(
      mix, conv_w, dt_b, A_log, norm_w, w_out, out);
}